// Round 4
// baseline (1868.717 us; speedup 1.0000x reference)
//
#include <hip/hip_runtime.h>
#include <math.h>

// fused attention block, MI355X. Round 3 (= round-2 code, desk-checked):
//   - QKV GEMM + out-proj GEMM on MFMA (split-bf16 hi/lo, 3-term: ~fp32 accuracy)
//   - attention kept fp32 VALU (numerically exact path; MFMA conversion next round)
// ws layout (144 MiB): qkv f32 96MiB | Wqkv hi/lo 12MiB | Wout hi/lo 4MiB |
//                      X hi/lo 32MiB (aliased by attn-out hi/lo after consumption)

#define ATT_SCALE 0.25f

typedef float v4f   __attribute__((ext_vector_type(4)));
typedef float f32x16 __attribute__((ext_vector_type(16)));
typedef short s4    __attribute__((ext_vector_type(4)));
typedef short bf8   __attribute__((ext_vector_type(8)));   // 8 bf16 = 16B (MFMA A/B frag)

__device__ __forceinline__ unsigned short bf16r(float f) {   // RNE f32->bf16
    unsigned int u = __float_as_uint(f);
    u += 0x7FFFu + ((u >> 16) & 1u);
    return (unsigned short)(u >> 16);
}
__device__ __forceinline__ float bf16f(unsigned short h) {
    return __uint_as_float(((unsigned int)h) << 16);
}

// ---------------------------------------------------------------------------
// split f32 -> (hi, lo) bf16 arrays. x = hi + lo to ~2^-17 relative.
// ---------------------------------------------------------------------------
__global__ __launch_bounds__(256) void convert_split(const float* __restrict__ in,
                                                     unsigned short* __restrict__ hi,
                                                     unsigned short* __restrict__ lo,
                                                     int n4) {
    const int i = blockIdx.x * 256 + threadIdx.x;
    if (i >= n4) return;
    v4f xv = ((const v4f*)in)[i];
    s4 h, l;
#pragma unroll
    for (int j = 0; j < 4; ++j) {
        unsigned short hv = bf16r(xv[j]);
        h[j] = (short)hv;
        l[j] = (short)bf16r(xv[j] - bf16f(hv));
    }
    ((s4*)hi)[i] = h;
    ((s4*)lo)[i] = l;
}

// ---------------------------------------------------------------------------
// Split-bf16 NT GEMM: out[m][j] = sum_k A[m][k]*B[j][k] + bias[j]
// A: [M][1024] hi/lo bf16, B: [N][1024] hi/lo bf16. Tile 128x128, BK=32.
// 4 waves (2x2), wave tile 64x64 = 2x2 frags of mfma_f32_32x32x16_bf16.
// 3-term split: hi*hi + hi*lo + lo*hi (lo*lo dropped, ~2^-18/product).
//
// LDS layout per operand array: 8 "blocks" (fi*2+ks) of 64 16B-slots; slot for
// (row r, 8k-piece kp) = block*64 + (kp&1)*32 + ((r&31) + 2*kp)&31  (ADD-rotate:
// read side lane-linear & conflict-free, write side small-way).
// Read: lane l, frag fi'=wm*2+im, ks: block fi'*2+ks, half lh=l>>5,
// rot=(l31+2*(2*ks+lh))&31 -> row=l31, k-piece 2*ks+lh == write's kp. Verified.
// C/D map (m74/m101): col=lane&31, row=(reg&3)+8*(reg>>2)+4*(lane>>5).
// ---------------------------------------------------------------------------
__global__ __launch_bounds__(256) void gemm_split(
    const unsigned short* __restrict__ Ahi, const unsigned short* __restrict__ Alo,
    const unsigned short* __restrict__ Bhi, const unsigned short* __restrict__ Blo,
    const float* __restrict__ bias, float* __restrict__ out, int mode) {
    __shared__ unsigned short lAh[4096], lAl[4096], lBh[4096], lBl[4096];  // 4x8KB

    const int m0 = blockIdx.y * 128;
    const int j0 = blockIdx.x * 128;
    const int t  = threadIdx.x;

    // staging mapping: thread t handles k-piece kp (8 bf16) of rows r0, r0+64
    const int kp  = t & 3;
    const int r0  = t >> 2;          // 0..63
    const int sks = kp >> 1, skh = kp & 1;

    // compute mapping
    const int l   = t & 63;
    const int wid = t >> 6;
    const int wm  = wid >> 1, wn = wid & 1;
    const int l31 = l & 31, lh = l >> 5;

    int offA[2][2], offB[2][2];      // [frag][ks] -> ushort offset
#pragma unroll
    for (int im = 0; im < 2; ++im)
#pragma unroll
        for (int ks = 0; ks < 2; ++ks) {
            const int kpr = ks * 2 + lh;
            const int rot = (l31 + 2 * kpr) & 31;
            offA[im][ks] = ((((wm*2+im)*2+ks)*64) + lh*32 + rot) * 8;
            offB[im][ks] = ((((wn*2+im)*2+ks)*64) + lh*32 + rot) * 8;
        }

    f32x16 acc[2][2];
#pragma unroll
    for (int i = 0; i < 2; ++i)
#pragma unroll
        for (int j = 0; j < 2; ++j)
#pragma unroll
            for (int r = 0; r < 16; ++r) acc[i][j][r] = 0.f;

    for (int kt = 0; kt < 32; ++kt) {
        __syncthreads();
        const int kb = kt * 32 + kp * 8;
#pragma unroll
        for (int hh = 0; hh < 2; ++hh) {
            const int r  = r0 + hh * 64;
            const int sl = (((r >> 5) * 2 + sks) * 64 + skh * 32 + (((r & 31) + 2 * kp) & 31)) * 8;
            const size_t ga = (size_t)(m0 + r) * 1024 + kb;
            const size_t gb = (size_t)(j0 + r) * 1024 + kb;
            *(bf8*)(lAh + sl) = *(const bf8*)(Ahi + ga);
            *(bf8*)(lAl + sl) = *(const bf8*)(Alo + ga);
            *(bf8*)(lBh + sl) = *(const bf8*)(Bhi + gb);
            *(bf8*)(lBl + sl) = *(const bf8*)(Blo + gb);
        }
        __syncthreads();
#pragma unroll
        for (int ks = 0; ks < 2; ++ks) {
            bf8 ah[2], al2[2], bh[2], bl2[2];
#pragma unroll
            for (int im = 0; im < 2; ++im) {
                ah[im]  = *(const bf8*)(lAh + offA[im][ks]);
                al2[im] = *(const bf8*)(lAl + offA[im][ks]);
                bh[im]  = *(const bf8*)(lBh + offB[im][ks]);
                bl2[im] = *(const bf8*)(lBl + offB[im][ks]);
            }
#pragma unroll
            for (int im = 0; im < 2; ++im)
#pragma unroll
                for (int jn = 0; jn < 2; ++jn) {
                    acc[im][jn] = __builtin_amdgcn_mfma_f32_32x32x16_bf16(ah[im],  bh[jn],  acc[im][jn], 0, 0, 0);
                    acc[im][jn] = __builtin_amdgcn_mfma_f32_32x32x16_bf16(ah[im],  bl2[jn], acc[im][jn], 0, 0, 0);
                    acc[im][jn] = __builtin_amdgcn_mfma_f32_32x32x16_bf16(al2[im], bh[jn],  acc[im][jn], 0, 0, 0);
                }
        }
    }

    // epilogue: bias + store. mode 0: plain [M][1024]; mode 1: qkv scatter.
#pragma unroll
    for (int im = 0; im < 2; ++im)
#pragma unroll
        for (int jn = 0; jn < 2; ++jn) {
            const int col   = j0 + wn * 64 + jn * 32 + l31;
            const float bv  = bias[col];
            const int rbase = m0 + wm * 64 + im * 32 + 4 * lh;
            if (mode == 0) {
#pragma unroll
                for (int reg = 0; reg < 16; ++reg) {
                    const int row = rbase + (reg & 3) + 8 * (reg >> 2);
                    out[(size_t)row * 1024 + col] = acc[im][jn][reg] + bv;
                }
            } else {
                const int which = col >> 10, hcol = (col & 1023) >> 6, dd = col & 63;
                // tile never crosses a batch boundary (2048 % 128 == 0)
                const size_t base = (((size_t)which * 64 + (rbase >> 11) * 16 + hcol) * 2048) * 64 + dd;
#pragma unroll
                for (int reg = 0; reg < 16; ++reg) {
                    const int row = rbase + (reg & 3) + 8 * (reg >> 2);
                    out[base + (size_t)(row & 2047) * 64] = acc[im][jn][reg] + bv;
                }
            }
        }
}

// ---------------------------------------------------------------------------
// Kernel: flash attention per (b,h), fp32. 64 q-rows/block, K/V tiles of 64.
// qkv layout: [3][BH=64][N=2048][HD=64] f32. Output: hi/lo bf16 [B][N][D].
// ---------------------------------------------------------------------------
__global__ __launch_bounds__(256) void attn_kernel(const float* __restrict__ qkv,
                                                   unsigned short* __restrict__ attn_hi,
                                                   unsigned short* __restrict__ attn_lo) {
    __shared__ float Qs[64][68];   // [d][r]
    __shared__ float Ks[64][68];   // [d][c]
    __shared__ float Vs[64][68];   // [k][dd]
    __shared__ float Ps[64][68];   // [r][c]

    const int bh = blockIdx.y;
    const int n0 = blockIdx.x * 64;
    const float* qb = qkv + ((size_t)(0 * 64 + bh)) * 2048 * 64;
    const float* kb = qkv + ((size_t)(1 * 64 + bh)) * 2048 * 64;
    const float* vb = qkv + ((size_t)(2 * 64 + bh)) * 2048 * 64;

    const int t  = threadIdx.x;
    const int tx = t & 15, ty = t >> 4;
    const int dq = t & 15, rq = t >> 4;

#pragma unroll
    for (int hh = 0; hh < 4; ++hh) {
        const int r = rq + hh * 16;
        v4f q = *(const v4f*)(qb + (size_t)(n0 + r) * 64 + dq * 4);
        Qs[dq*4+0][r] = q[0]; Qs[dq*4+1][r] = q[1];
        Qs[dq*4+2][r] = q[2]; Qs[dq*4+3][r] = q[3];
    }

    float m_run[4], l_run[4], O[4][4];
#pragma unroll
    for (int ii = 0; ii < 4; ++ii) {
        m_run[ii] = -INFINITY; l_run[ii] = 0.f;
#pragma unroll
        for (int jj = 0; jj < 4; ++jj) O[ii][jj] = 0.f;
    }

    for (int kt = 0; kt < 32; ++kt) {
        __syncthreads();
        const float* kbt = kb + (size_t)kt * 64 * 64;
        const float* vbt = vb + (size_t)kt * 64 * 64;
#pragma unroll
        for (int hh = 0; hh < 4; ++hh) {
            const int r = rq + hh * 16;
            v4f kv = *(const v4f*)(kbt + (size_t)r * 64 + dq * 4);
            Ks[dq*4+0][r] = kv[0]; Ks[dq*4+1][r] = kv[1];
            Ks[dq*4+2][r] = kv[2]; Ks[dq*4+3][r] = kv[3];
            v4f vv = *(const v4f*)(vbt + (size_t)r * 64 + dq * 4);
            *(v4f*)&Vs[r][dq * 4] = vv;
        }
        __syncthreads();

        float s[4][4] = {};
#pragma unroll
        for (int d = 0; d < 64; ++d) {
            v4f a = *(const v4f*)&Qs[d][ty * 4];
            v4f b = *(const v4f*)&Ks[d][tx * 4];
#pragma unroll
            for (int ii = 0; ii < 4; ++ii)
#pragma unroll
                for (int jj = 0; jj < 4; ++jj)
                    s[ii][jj] = fmaf(a[ii], b[jj], s[ii][jj]);
        }
#pragma unroll
        for (int ii = 0; ii < 4; ++ii)
#pragma unroll
            for (int jj = 0; jj < 4; ++jj) s[ii][jj] *= ATT_SCALE;

#pragma unroll
        for (int ii = 0; ii < 4; ++ii) {
            float rm = fmaxf(fmaxf(s[ii][0], s[ii][1]), fmaxf(s[ii][2], s[ii][3]));
#pragma unroll
            for (int off = 1; off < 16; off <<= 1) rm = fmaxf(rm, __shfl_xor(rm, off));
            const float mn   = fmaxf(m_run[ii], rm);
            const float corr = __expf(m_run[ii] - mn);
            float rs = 0.f;
#pragma unroll
            for (int jj = 0; jj < 4; ++jj) {
                const float p = __expf(s[ii][jj] - mn);
                s[ii][jj] = p; rs += p;
            }
#pragma unroll
            for (int off = 1; off < 16; off <<= 1) rs += __shfl_xor(rs, off);
            l_run[ii] = l_run[ii] * corr + rs;
            m_run[ii] = mn;
#pragma unroll
            for (int jj = 0; jj < 4; ++jj) O[ii][jj] *= corr;
            *(v4f*)&Ps[ty * 4 + ii][tx * 4] = *(v4f*)&s[ii][0];
        }
        __syncthreads();

#pragma unroll
        for (int k = 0; k < 64; k += 4) {
            v4f p[4], vv[4];
#pragma unroll
            for (int ii = 0; ii < 4; ++ii) p[ii] = *(const v4f*)&Ps[ty * 4 + ii][k];
#pragma unroll
            for (int kk = 0; kk < 4; ++kk) vv[kk] = *(const v4f*)&Vs[k + kk][tx * 4];
#pragma unroll
            for (int ii = 0; ii < 4; ++ii)
#pragma unroll
                for (int kk = 0; kk < 4; ++kk)
#pragma unroll
                    for (int jj = 0; jj < 4; ++jj)
                        O[ii][jj] = fmaf(p[ii][kk], vv[kk][jj], O[ii][jj]);
        }
    }

    // epilogue: normalize + split to hi/lo bf16 for the MFMA out-proj
    const int bb = bh >> 4, hd = bh & 15;
#pragma unroll
    for (int ii = 0; ii < 4; ++ii) {
        const float inv = 1.0f / l_run[ii];
        s4 vh, vl;
#pragma unroll
        for (int jj = 0; jj < 4; ++jj) {
            const float v = O[ii][jj] * inv;
            const unsigned short hv = bf16r(v);
            vh[jj] = (short)hv;
            vl[jj] = (short)bf16r(v - bf16f(hv));
        }
        const size_t idx = ((size_t)bb * 2048 + n0 + ty * 4 + ii) * 1024 + hd * 64 + tx * 4;
        *(s4*)(attn_hi + idx) = vh;
        *(s4*)(attn_lo + idx) = vl;
    }
}

// ---------------------------------------------------------------------------
extern "C" void kernel_launch(void* const* d_in, const int* in_sizes, int n_in,
                              void* d_out, int out_size, void* d_ws, size_t ws_size,
                              hipStream_t stream) {
    const float* x     = (const float*)d_in[0];
    const float* w_qkv = (const float*)d_in[1];
    const float* b_qkv = (const float*)d_in[2];
    const float* w_out = (const float*)d_in[3];
    const float* b_out = (const float*)d_in[4];
    float* out = (float*)d_out;

    char* ws = (char*)d_ws;
    float* qkv = (float*)ws;                 ws += (size_t)3 * 64 * 2048 * 64 * 4;  // 96 MiB
    unsigned short* Wqh = (unsigned short*)ws; ws += (size_t)3072 * 1024 * 2;
    unsigned short* Wql = (unsigned short*)ws; ws += (size_t)3072 * 1024 * 2;
    unsigned short* Woh = (unsigned short*)ws; ws += (size_t)1024 * 1024 * 2;
    unsigned short* Wol = (unsigned short*)ws; ws += (size_t)1024 * 1024 * 2;
    unsigned short* Xhi = (unsigned short*)ws; ws += (size_t)8192 * 1024 * 2;
    unsigned short* Xlo = (unsigned short*)ws;
    // X consumed by qkv_gemm before attention writes its output -> alias:
    unsigned short* AThi = Xhi;
    unsigned short* ATlo = Xlo;

    convert_split<<<8192, 256, 0, stream>>>(x,     Xhi, Xlo, 2097152);
    convert_split<<<3072, 256, 0, stream>>>(w_qkv, Wqh, Wql, 786432);
    convert_split<<<1024, 256, 0, stream>>>(w_out, Woh, Wol, 262144);
    gemm_split<<<dim3(24, 64), 256, 0, stream>>>(Xhi, Xlo, Wqh, Wql, b_qkv, qkv, 1);
    attn_kernel<<<dim3(32, 64), 256, 0, stream>>>(qkv, AThi, ATlo);
    gemm_split<<<dim3(8, 64), 256, 0, stream>>>(AThi, ATlo, Woh, Wol, b_out, out, 0);
}

// Round 5
// 923.278 us; speedup vs baseline: 2.0240x; 2.0240x over previous
//
#include <hip/hip_runtime.h>
#include <math.h>

// fused attention block, MI355X. Round 4:
//   - QKV GEMM emits pre-split hi/lo bf16 Q (x0.25 folded), K, and V TRANSPOSED [bh][dd][n]
//   - attention: MFMA (32x32x16 bf16, 3-term hi/lo split) for QK^T and PV,
//     online softmax fp32 VALU, P split hi/lo through per-wave LDS
//   - out-proj GEMM unchanged (verified last round)
// ws (144 MiB): Qhi Qlo Khi Klo (16MiB ea) | Vthi Vtlo (16MiB ea) |
//               Wqkv hi/lo 12MiB | Wout hi/lo 4MiB | X hi/lo 32MiB (aliased by attn-out)

typedef float v4f    __attribute__((ext_vector_type(4)));
typedef float f32x16 __attribute__((ext_vector_type(16)));
typedef short s4     __attribute__((ext_vector_type(4)));
typedef short bf8    __attribute__((ext_vector_type(8)));   // 8 bf16 = 16B MFMA frag

__device__ __forceinline__ unsigned short bf16r(float f) {   // RNE f32->bf16
    unsigned int u = __float_as_uint(f);
    u += 0x7FFFu + ((u >> 16) & 1u);
    return (unsigned short)(u >> 16);
}
__device__ __forceinline__ float bf16f(unsigned short h) {
    return __uint_as_float(((unsigned int)h) << 16);
}

// ---------------------------------------------------------------------------
__global__ __launch_bounds__(256) void convert_split(const float* __restrict__ in,
                                                     unsigned short* __restrict__ hi,
                                                     unsigned short* __restrict__ lo,
                                                     int n4) {
    const int i = blockIdx.x * 256 + threadIdx.x;
    if (i >= n4) return;
    v4f xv = ((const v4f*)in)[i];
    s4 h, l;
#pragma unroll
    for (int j = 0; j < 4; ++j) {
        unsigned short hv = bf16r(xv[j]);
        h[j] = (short)hv;
        l[j] = (short)bf16r(xv[j] - bf16f(hv));
    }
    ((s4*)hi)[i] = h;
    ((s4*)lo)[i] = l;
}

// ---------------------------------------------------------------------------
// GEMM core (verified round 4): 128x128 tile, BK=32, 4 waves 2x2, 3-term split.
// LDS rotate layout: slot(r,kp) = ((r>>5)*2 + (kp>>1))*64 + (kp&1)*32 + ((r&31)+2kp)&31
// ---------------------------------------------------------------------------
#define GEMM_CORE(AHI, ALO, BHI, BLO)                                                      \
    __shared__ unsigned short lAh[4096], lAl[4096], lBh[4096], lBl[4096];                  \
    const int m0 = blockIdx.y * 128;                                                       \
    const int j0 = blockIdx.x * 128;                                                       \
    const int t  = threadIdx.x;                                                            \
    const int kp  = t & 3;                                                                 \
    const int r0  = t >> 2;                                                                \
    const int sks = kp >> 1, skh = kp & 1;                                                 \
    const int l   = t & 63;                                                                \
    const int wid = t >> 6;                                                                \
    const int wm  = wid >> 1, wn = wid & 1;                                                \
    const int l31 = l & 31, lh = l >> 5;                                                   \
    int offA[2][2], offB[2][2];                                                            \
    _Pragma("unroll") for (int im = 0; im < 2; ++im)                                       \
    _Pragma("unroll") for (int ks = 0; ks < 2; ++ks) {                                     \
        const int kpr = ks * 2 + lh;                                                       \
        const int rot = (l31 + 2 * kpr) & 31;                                              \
        offA[im][ks] = ((((wm*2+im)*2+ks)*64) + lh*32 + rot) * 8;                          \
        offB[im][ks] = ((((wn*2+im)*2+ks)*64) + lh*32 + rot) * 8;                          \
    }                                                                                      \
    f32x16 acc[2][2];                                                                      \
    _Pragma("unroll") for (int i = 0; i < 2; ++i)                                          \
    _Pragma("unroll") for (int j = 0; j < 2; ++j)                                          \
    _Pragma("unroll") for (int r = 0; r < 16; ++r) acc[i][j][r] = 0.f;                     \
    for (int kt = 0; kt < 32; ++kt) {                                                      \
        __syncthreads();                                                                   \
        const int kb = kt * 32 + kp * 8;                                                   \
        _Pragma("unroll") for (int hh = 0; hh < 2; ++hh) {                                 \
            const int r  = r0 + hh * 64;                                                   \
            const int sl = (((r >> 5) * 2 + sks) * 64 + skh * 32 + (((r & 31) + 2 * kp) & 31)) * 8; \
            const size_t ga = (size_t)(m0 + r) * 1024 + kb;                                \
            const size_t gb = (size_t)(j0 + r) * 1024 + kb;                                \
            *(bf8*)(lAh + sl) = *(const bf8*)(AHI + ga);                                   \
            *(bf8*)(lAl + sl) = *(const bf8*)(ALO + ga);                                   \
            *(bf8*)(lBh + sl) = *(const bf8*)(BHI + gb);                                   \
            *(bf8*)(lBl + sl) = *(const bf8*)(BLO + gb);                                   \
        }                                                                                  \
        __syncthreads();                                                                   \
        _Pragma("unroll") for (int ks = 0; ks < 2; ++ks) {                                 \
            bf8 ah[2], al2[2], bh[2], bl2[2];                                              \
            _Pragma("unroll") for (int im = 0; im < 2; ++im) {                             \
                ah[im]  = *(const bf8*)(lAh + offA[im][ks]);                               \
                al2[im] = *(const bf8*)(lAl + offA[im][ks]);                               \
                bh[im]  = *(const bf8*)(lBh + offB[im][ks]);                               \
                bl2[im] = *(const bf8*)(lBl + offB[im][ks]);                               \
            }                                                                              \
            _Pragma("unroll") for (int im = 0; im < 2; ++im)                               \
            _Pragma("unroll") for (int jn = 0; jn < 2; ++jn) {                             \
                acc[im][jn] = __builtin_amdgcn_mfma_f32_32x32x16_bf16(ah[im],  bh[jn],  acc[im][jn], 0, 0, 0); \
                acc[im][jn] = __builtin_amdgcn_mfma_f32_32x32x16_bf16(ah[im],  bl2[jn], acc[im][jn], 0, 0, 0); \
                acc[im][jn] = __builtin_amdgcn_mfma_f32_32x32x16_bf16(al2[im], bh[jn],  acc[im][jn], 0, 0, 0); \
            }                                                                              \
        }                                                                                  \
    }

// ---------------------------------------------------------------------------
// QKV GEMM: writes Q (x0.25, split), K (split), Vt (split, transposed [bh][dd][n])
// ---------------------------------------------------------------------------
__global__ __launch_bounds__(256) void gemm_qkv(
    const unsigned short* __restrict__ Ahi, const unsigned short* __restrict__ Alo,
    const unsigned short* __restrict__ Bhi, const unsigned short* __restrict__ Blo,
    const float* __restrict__ bias,
    unsigned short* __restrict__ Qhi, unsigned short* __restrict__ Qlo,
    unsigned short* __restrict__ Khi, unsigned short* __restrict__ Klo,
    unsigned short* __restrict__ Vhi, unsigned short* __restrict__ Vlo) {
    GEMM_CORE(Ahi, Alo, Bhi, Blo)
#pragma unroll
    for (int im = 0; im < 2; ++im)
#pragma unroll
        for (int jn = 0; jn < 2; ++jn) {
            const int col   = j0 + wn * 64 + jn * 32 + l31;
            const float bv  = bias[col];
            const int rbase = m0 + wm * 64 + im * 32 + 4 * lh;
            const int which = col >> 10;
            const int hcol  = (col & 1023) >> 6;
            const int dd    = col & 63;
            const int bh    = (rbase >> 11) * 16 + hcol;    // tile within one batch
#pragma unroll
            for (int reg = 0; reg < 16; ++reg) {
                const int row = rbase + (reg & 3) + 8 * (reg >> 2);
                const int n   = row & 2047;
                float val = acc[im][jn][reg] + bv;
                if (which == 0) val *= 0.25f;               // fold ATT_SCALE into Q (exact)
                const unsigned short hv = bf16r(val);
                const unsigned short lv = bf16r(val - bf16f(hv));
                if (which == 0) {
                    const size_t idx = (size_t)bh * 131072 + (size_t)n * 64 + dd;
                    Qhi[idx] = hv; Qlo[idx] = lv;
                } else if (which == 1) {
                    const size_t idx = (size_t)bh * 131072 + (size_t)n * 64 + dd;
                    Khi[idx] = hv; Klo[idx] = lv;
                } else {
                    const size_t idx = (size_t)bh * 131072 + (size_t)dd * 2048 + n;
                    Vhi[idx] = hv; Vlo[idx] = lv;
                }
            }
        }
}

// ---------------------------------------------------------------------------
// Output projection GEMM (verified): plain f32 [M][1024] epilogue
// ---------------------------------------------------------------------------
__global__ __launch_bounds__(256) void gemm_out(
    const unsigned short* __restrict__ Ahi, const unsigned short* __restrict__ Alo,
    const unsigned short* __restrict__ Bhi, const unsigned short* __restrict__ Blo,
    const float* __restrict__ bias, float* __restrict__ out) {
    GEMM_CORE(Ahi, Alo, Bhi, Blo)
#pragma unroll
    for (int im = 0; im < 2; ++im)
#pragma unroll
        for (int jn = 0; jn < 2; ++jn) {
            const int col   = j0 + wn * 64 + jn * 32 + l31;
            const float bv  = bias[col];
            const int rbase = m0 + wm * 64 + im * 32 + 4 * lh;
#pragma unroll
            for (int reg = 0; reg < 16; ++reg) {
                const int row = rbase + (reg & 3) + 8 * (reg >> 2);
                out[(size_t)row * 1024 + col] = acc[im][jn][reg] + bv;
            }
        }
}

// ---------------------------------------------------------------------------
// MFMA flash attention. Block: 128 q-rows x one bh; 4 waves x 32 q-rows.
// KV tile 64. K/Vt staged in rotate-layout LDS (conflict-free b128 frags).
// Tile LDS slot(r,kp) = ((r>>5)*8 + kp)*32 + ((r&31)+2*kp)&31   (16B slots)
// Online softmax: rows live in 32-lane halves (C-map row=(reg&3)+8(reg>>2)+4lh),
// 5-step shfl_xor reductions. P split hi/lo via per-wave LDS (no barrier).
// ---------------------------------------------------------------------------
__global__ __launch_bounds__(256, 2) void attn_mfma(
    const unsigned short* __restrict__ Qhi, const unsigned short* __restrict__ Qlo,
    const unsigned short* __restrict__ Khi, const unsigned short* __restrict__ Klo,
    const unsigned short* __restrict__ Vhi, const unsigned short* __restrict__ Vlo,
    unsigned short* __restrict__ Ohi, unsigned short* __restrict__ Olo) {
    __shared__ unsigned short Kh_s[4096], Kl_s[4096], Vh_s[4096], Vl_s[4096];  // 32 KB
    __shared__ unsigned short Ph_s[4][2048], Pl_s[4][2048];                    // 32 KB

    const int bh = blockIdx.y;
    const int q0 = blockIdx.x * 128;
    const int t  = threadIdx.x;
    const int w  = t >> 6, l = t & 63, l31 = l & 31, lh = l >> 5;
    const size_t bhbase = (size_t)bh * 131072;

    // hoist Q fragments (A-operand: lane l holds Q[q0+w*32+l31][k = ks*16+lh*8 ..+8])
    bf8 qh[4], ql[4];
    {
        const size_t qb = bhbase + (size_t)(q0 + w * 32 + l31) * 64 + lh * 8;
#pragma unroll
        for (int ks = 0; ks < 4; ++ks) {
            qh[ks] = *(const bf8*)(Qhi + qb + ks * 16);
            ql[ks] = *(const bf8*)(Qlo + qb + ks * 16);
        }
    }

    float m_run[16], l_run[16];
    f32x16 O0, O1;
#pragma unroll
    for (int r = 0; r < 16; ++r) { m_run[r] = -INFINITY; l_run[r] = 0.f; O0[r] = 0.f; O1[r] = 0.f; }

    unsigned short* const ph = Ph_s[w];
    unsigned short* const pl = Pl_s[w];

    for (int kt = 0; kt < 32; ++kt) {
        const int k0 = kt * 64;
        __syncthreads();
#pragma unroll
        for (int pass = 0; pass < 2; ++pass) {
            const int c  = pass * 256 + t;
            const int r  = c >> 3, kpc = c & 7;
            const int sl = (((r >> 5) * 8 + kpc) * 32 + (((r & 31) + 2 * kpc) & 31)) * 8;
            const size_t gk = bhbase + (size_t)(k0 + r) * 64 + kpc * 8;
            *(bf8*)(Kh_s + sl) = *(const bf8*)(Khi + gk);
            *(bf8*)(Kl_s + sl) = *(const bf8*)(Klo + gk);
            const size_t gv = bhbase + (size_t)r * 2048 + k0 + kpc * 8;   // r = dd
            *(bf8*)(Vh_s + sl) = *(const bf8*)(Vhi + gv);
            *(bf8*)(Vl_s + sl) = *(const bf8*)(Vlo + gv);
        }
        __syncthreads();

        // ---- S = Q K^T (3-term). C: col=kv(jn*32+l31), row=(reg&3)+8(reg>>2)+4lh
        f32x16 s0, s1;
#pragma unroll
        for (int r = 0; r < 16; ++r) { s0[r] = 0.f; s1[r] = 0.f; }
#pragma unroll
        for (int ks = 0; ks < 4; ++ks) {
            const int kpf = ks * 2 + lh;
            const int rot = (l31 + 2 * kpf) & 31;
            const int b0  = ((0 * 8 + kpf) * 32 + rot) * 8;
            const int b1  = ((1 * 8 + kpf) * 32 + rot) * 8;
            const bf8 kh0 = *(const bf8*)(Kh_s + b0), kl0 = *(const bf8*)(Kl_s + b0);
            const bf8 kh1 = *(const bf8*)(Kh_s + b1), kl1 = *(const bf8*)(Kl_s + b1);
            s0 = __builtin_amdgcn_mfma_f32_32x32x16_bf16(qh[ks], kh0, s0, 0, 0, 0);
            s0 = __builtin_amdgcn_mfma_f32_32x32x16_bf16(qh[ks], kl0, s0, 0, 0, 0);
            s0 = __builtin_amdgcn_mfma_f32_32x32x16_bf16(ql[ks], kh0, s0, 0, 0, 0);
            s1 = __builtin_amdgcn_mfma_f32_32x32x16_bf16(qh[ks], kh1, s1, 0, 0, 0);
            s1 = __builtin_amdgcn_mfma_f32_32x32x16_bf16(qh[ks], kl1, s1, 0, 0, 0);
            s1 = __builtin_amdgcn_mfma_f32_32x32x16_bf16(ql[ks], kh1, s1, 0, 0, 0);
        }

        // ---- online softmax (rows in 32-lane halves; shfl masks stay in-half)
        float tm[16], corr[16], rs[16];
#pragma unroll
        for (int r = 0; r < 16; ++r) tm[r] = fmaxf(s0[r], s1[r]);
#pragma unroll
        for (int mk = 1; mk <= 16; mk <<= 1)
#pragma unroll
            for (int r = 0; r < 16; ++r) tm[r] = fmaxf(tm[r], __shfl_xor(tm[r], mk));
#pragma unroll
        for (int r = 0; r < 16; ++r) {
            const float mn = fmaxf(m_run[r], tm[r]);
            corr[r] = __expf(m_run[r] - mn);    // 0 on first tile (-inf - finite)
            m_run[r] = mn;
        }
#pragma unroll
        for (int r = 0; r < 16; ++r) {
            s0[r] = __expf(s0[r] - m_run[r]);
            s1[r] = __expf(s1[r] - m_run[r]);
            rs[r] = s0[r] + s1[r];
        }
#pragma unroll
        for (int mk = 1; mk <= 16; mk <<= 1)
#pragma unroll
            for (int r = 0; r < 16; ++r) rs[r] += __shfl_xor(rs[r], mk);
#pragma unroll
        for (int r = 0; r < 16; ++r) {
            l_run[r] = l_run[r] * corr[r] + rs[r];
            O0[r] *= corr[r];
            O1[r] *= corr[r];
        }

        // ---- P -> per-wave LDS, split hi/lo (write slot(q,kv); wave-private)
#pragma unroll
        for (int r = 0; r < 16; ++r) {
            const int q = (r & 3) + 8 * (r >> 2) + 4 * lh;
            {
                const int kv = l31;
                const int kpp = kv >> 3;
                const int idx = (kpp * 32 + ((q + 2 * kpp) & 31)) * 8 + (kv & 7);
                const unsigned short hv = bf16r(s0[r]);
                ph[idx] = hv; pl[idx] = bf16r(s0[r] - bf16f(hv));
            }
            {
                const int kv = 32 + l31;
                const int kpp = kv >> 3;
                const int idx = (kpp * 32 + ((q + 2 * kpp) & 31)) * 8 + (kv & 7);
                const unsigned short hv = bf16r(s1[r]);
                ph[idx] = hv; pl[idx] = bf16r(s1[r] - bf16f(hv));
            }
        }

        // ---- O += P V (3-term). A=P[q][kv], B=Vt[dd][kv]; C col=dd, rows=q
#pragma unroll
        for (int ks = 0; ks < 4; ++ks) {
            const int kpf = ks * 2 + lh;
            const int rot = (l31 + 2 * kpf) & 31;
            const int pidx = (kpf * 32 + rot) * 8;
            const bf8 pah = *(const bf8*)(ph + pidx);
            const bf8 pal = *(const bf8*)(pl + pidx);
            const int v0 = ((0 * 8 + kpf) * 32 + rot) * 8;
            const int v1 = ((1 * 8 + kpf) * 32 + rot) * 8;
            const bf8 vh0 = *(const bf8*)(Vh_s + v0), vl0 = *(const bf8*)(Vl_s + v0);
            const bf8 vh1 = *(const bf8*)(Vh_s + v1), vl1 = *(const bf8*)(Vl_s + v1);
            O0 = __builtin_amdgcn_mfma_f32_32x32x16_bf16(pah, vh0, O0, 0, 0, 0);
            O0 = __builtin_amdgcn_mfma_f32_32x32x16_bf16(pah, vl0, O0, 0, 0, 0);
            O0 = __builtin_amdgcn_mfma_f32_32x32x16_bf16(pal, vh0, O0, 0, 0, 0);
            O1 = __builtin_amdgcn_mfma_f32_32x32x16_bf16(pah, vh1, O1, 0, 0, 0);
            O1 = __builtin_amdgcn_mfma_f32_32x32x16_bf16(pah, vl1, O1, 0, 0, 0);
            O1 = __builtin_amdgcn_mfma_f32_32x32x16_bf16(pal, vh1, O1, 0, 0, 0);
        }
    }

    // ---- epilogue: normalize, split hi/lo, store [B][N][1024]
    const int b = bh >> 4, h = bh & 15;
#pragma unroll
    for (int r = 0; r < 16; ++r) {
        const int q = (r & 3) + 8 * (r >> 2) + 4 * lh;
        const int n = q0 + w * 32 + q;
        const float inv = 1.f / l_run[r];
        const size_t base = ((size_t)b * 2048 + n) * 1024 + h * 64;
        const float v0 = O0[r] * inv, v1 = O1[r] * inv;
        const unsigned short h0 = bf16r(v0), h1 = bf16r(v1);
        Ohi[base + l31]      = h0;  Olo[base + l31]      = bf16r(v0 - bf16f(h0));
        Ohi[base + 32 + l31] = h1;  Olo[base + 32 + l31] = bf16r(v1 - bf16f(h1));
    }
}

// ---------------------------------------------------------------------------
extern "C" void kernel_launch(void* const* d_in, const int* in_sizes, int n_in,
                              void* d_out, int out_size, void* d_ws, size_t ws_size,
                              hipStream_t stream) {
    const float* x     = (const float*)d_in[0];
    const float* w_qkv = (const float*)d_in[1];
    const float* b_qkv = (const float*)d_in[2];
    const float* w_out = (const float*)d_in[3];
    const float* b_out = (const float*)d_in[4];
    float* out = (float*)d_out;

    char* ws = (char*)d_ws;
    unsigned short* Qhi = (unsigned short*)ws; ws += (size_t)8388608 * 2;   // 16 MiB
    unsigned short* Qlo = (unsigned short*)ws; ws += (size_t)8388608 * 2;
    unsigned short* Khi = (unsigned short*)ws; ws += (size_t)8388608 * 2;
    unsigned short* Klo = (unsigned short*)ws; ws += (size_t)8388608 * 2;
    unsigned short* Vhi = (unsigned short*)ws; ws += (size_t)8388608 * 2;
    unsigned short* Vlo = (unsigned short*)ws; ws += (size_t)8388608 * 2;
    unsigned short* Wqh = (unsigned short*)ws; ws += (size_t)3145728 * 2;   // 6 MiB
    unsigned short* Wql = (unsigned short*)ws; ws += (size_t)3145728 * 2;
    unsigned short* Woh = (unsigned short*)ws; ws += (size_t)1048576 * 2;   // 2 MiB
    unsigned short* Wol = (unsigned short*)ws; ws += (size_t)1048576 * 2;
    unsigned short* Xhi = (unsigned short*)ws; ws += (size_t)8388608 * 2;   // 16 MiB
    unsigned short* Xlo = (unsigned short*)ws;
    // X consumed by gemm_qkv before attention writes -> alias attn output:
    unsigned short* AThi = Xhi;
    unsigned short* ATlo = Xlo;

    convert_split<<<8192, 256, 0, stream>>>(x,     Xhi, Xlo, 2097152);
    convert_split<<<3072, 256, 0, stream>>>(w_qkv, Wqh, Wql, 786432);
    convert_split<<<1024, 256, 0, stream>>>(w_out, Woh, Wol, 262144);
    gemm_qkv<<<dim3(24, 64), 256, 0, stream>>>(Xhi, Xlo, Wqh, Wql, b_qkv,
                                               Qhi, Qlo, Khi, Klo, Vhi, Vlo);
    attn_mfma<<<dim3(16, 64), 256, 0, stream>>>(Qhi, Qlo, Khi, Klo, Vhi, Vlo, AThi, ATlo);
    gemm_out<<<dim3(8, 64), 256, 0, stream>>>(AThi, ATlo, Woh, Wol, b_out, out);
}

// Round 6
// 626.397 us; speedup vs baseline: 2.9833x; 1.4739x over previous
//
#include <hip/hip_runtime.h>
#include <math.h>

// fused attention block, MI355X. Round 5:
//   - attention: swapped QK^T (mfma(K,Q)) -> lane-local softmax (1 shfl per reduce),
//     P-fragments built in-register (hi/lo packed, partner exchange via shfl_xor 32),
//     no P-LDS (32KB LDS total), V staged by gather-transpose from natural layout
//   - gemm_qkv now writes Q/K/V all in natural [bh][n][dd] (no scatter)
//   - gemm_out / converts unchanged (verified)
// ws (128 MiB): Q,K,V hi/lo 16MiB ea | Wqkv hi/lo 12MiB | Wout hi/lo 4MiB |
//               X hi/lo 32MiB (aliased by attn-out hi/lo after consumption)

typedef float v4f    __attribute__((ext_vector_type(4)));
typedef float f32x16 __attribute__((ext_vector_type(16)));
typedef short s4     __attribute__((ext_vector_type(4)));
typedef short bf8    __attribute__((ext_vector_type(8)));   // 8 bf16 = 16B MFMA frag

__device__ __forceinline__ unsigned short bf16r(float f) {   // RNE f32->bf16
    unsigned int u = __float_as_uint(f);
    u += 0x7FFFu + ((u >> 16) & 1u);
    return (unsigned short)(u >> 16);
}
__device__ __forceinline__ float bf16f(unsigned short h) {
    return __uint_as_float(((unsigned int)h) << 16);
}
// split a,b into packed-bf16 hi dword + residual-lo dword
__device__ __forceinline__ void split2(float a, float b, unsigned int& hi, unsigned int& lo) {
    const unsigned short ha = bf16r(a), hb = bf16r(b);
    hi = (unsigned int)ha | ((unsigned int)hb << 16);
    lo = (unsigned int)bf16r(a - bf16f(ha)) | ((unsigned int)bf16r(b - bf16f(hb)) << 16);
}

// ---------------------------------------------------------------------------
__global__ __launch_bounds__(256) void convert_split(const float* __restrict__ in,
                                                     unsigned short* __restrict__ hi,
                                                     unsigned short* __restrict__ lo,
                                                     int n4) {
    const int i = blockIdx.x * 256 + threadIdx.x;
    if (i >= n4) return;
    v4f xv = ((const v4f*)in)[i];
    s4 h, l;
#pragma unroll
    for (int j = 0; j < 4; ++j) {
        unsigned short hv = bf16r(xv[j]);
        h[j] = (short)hv;
        l[j] = (short)bf16r(xv[j] - bf16f(hv));
    }
    ((s4*)hi)[i] = h;
    ((s4*)lo)[i] = l;
}

// ---------------------------------------------------------------------------
// GEMM core (verified r4): 128x128 tile, BK=32, 4 waves 2x2, 3-term split.
// ---------------------------------------------------------------------------
#define GEMM_CORE(AHI, ALO, BHI, BLO)                                                      \
    __shared__ unsigned short lAh[4096], lAl[4096], lBh[4096], lBl[4096];                  \
    const int m0 = blockIdx.y * 128;                                                       \
    const int j0 = blockIdx.x * 128;                                                       \
    const int t  = threadIdx.x;                                                            \
    const int kp  = t & 3;                                                                 \
    const int r0  = t >> 2;                                                                \
    const int sks = kp >> 1, skh = kp & 1;                                                 \
    const int l   = t & 63;                                                                \
    const int wid = t >> 6;                                                                \
    const int wm  = wid >> 1, wn = wid & 1;                                                \
    const int l31 = l & 31, lh = l >> 5;                                                   \
    int offA[2][2], offB[2][2];                                                            \
    _Pragma("unroll") for (int im = 0; im < 2; ++im)                                       \
    _Pragma("unroll") for (int ks = 0; ks < 2; ++ks) {                                     \
        const int kpr = ks * 2 + lh;                                                       \
        const int rot = (l31 + 2 * kpr) & 31;                                              \
        offA[im][ks] = ((((wm*2+im)*2+ks)*64) + lh*32 + rot) * 8;                          \
        offB[im][ks] = ((((wn*2+im)*2+ks)*64) + lh*32 + rot) * 8;                          \
    }                                                                                      \
    f32x16 acc[2][2];                                                                      \
    _Pragma("unroll") for (int i = 0; i < 2; ++i)                                          \
    _Pragma("unroll") for (int j = 0; j < 2; ++j)                                          \
    _Pragma("unroll") for (int r = 0; r < 16; ++r) acc[i][j][r] = 0.f;                     \
    for (int kt = 0; kt < 32; ++kt) {                                                      \
        __syncthreads();                                                                   \
        const int kb = kt * 32 + kp * 8;                                                   \
        _Pragma("unroll") for (int hh = 0; hh < 2; ++hh) {                                 \
            const int r  = r0 + hh * 64;                                                   \
            const int sl = (((r >> 5) * 2 + sks) * 64 + skh * 32 + (((r & 31) + 2 * kp) & 31)) * 8; \
            const size_t ga = (size_t)(m0 + r) * 1024 + kb;                                \
            const size_t gb = (size_t)(j0 + r) * 1024 + kb;                                \
            *(bf8*)(lAh + sl) = *(const bf8*)(AHI + ga);                                   \
            *(bf8*)(lAl + sl) = *(const bf8*)(ALO + ga);                                   \
            *(bf8*)(lBh + sl) = *(const bf8*)(BHI + gb);                                   \
            *(bf8*)(lBl + sl) = *(const bf8*)(BLO + gb);                                   \
        }                                                                                  \
        __syncthreads();                                                                   \
        _Pragma("unroll") for (int ks = 0; ks < 2; ++ks) {                                 \
            bf8 ah[2], al2[2], bh[2], bl2[2];                                              \
            _Pragma("unroll") for (int im = 0; im < 2; ++im) {                             \
                ah[im]  = *(const bf8*)(lAh + offA[im][ks]);                               \
                al2[im] = *(const bf8*)(lAl + offA[im][ks]);                               \
                bh[im]  = *(const bf8*)(lBh + offB[im][ks]);                               \
                bl2[im] = *(const bf8*)(lBl + offB[im][ks]);                               \
            }                                                                              \
            _Pragma("unroll") for (int im = 0; im < 2; ++im)                               \
            _Pragma("unroll") for (int jn = 0; jn < 2; ++jn) {                             \
                acc[im][jn] = __builtin_amdgcn_mfma_f32_32x32x16_bf16(ah[im],  bh[jn],  acc[im][jn], 0, 0, 0); \
                acc[im][jn] = __builtin_amdgcn_mfma_f32_32x32x16_bf16(ah[im],  bl2[jn], acc[im][jn], 0, 0, 0); \
                acc[im][jn] = __builtin_amdgcn_mfma_f32_32x32x16_bf16(al2[im], bh[jn],  acc[im][jn], 0, 0, 0); \
            }                                                                              \
        }                                                                                  \
    }

// ---------------------------------------------------------------------------
// QKV GEMM: Q (x0.25 folded), K, V all split hi/lo, natural [bh][n][64] layout
// ---------------------------------------------------------------------------
__global__ __launch_bounds__(256) void gemm_qkv(
    const unsigned short* __restrict__ Ahi, const unsigned short* __restrict__ Alo,
    const unsigned short* __restrict__ Bhi, const unsigned short* __restrict__ Blo,
    const float* __restrict__ bias,
    unsigned short* __restrict__ Qhi, unsigned short* __restrict__ Qlo,
    unsigned short* __restrict__ Khi, unsigned short* __restrict__ Klo,
    unsigned short* __restrict__ Vhi, unsigned short* __restrict__ Vlo) {
    GEMM_CORE(Ahi, Alo, Bhi, Blo)
#pragma unroll
    for (int im = 0; im < 2; ++im)
#pragma unroll
        for (int jn = 0; jn < 2; ++jn) {
            const int col   = j0 + wn * 64 + jn * 32 + l31;
            const float bv  = bias[col];
            const int rbase = m0 + wm * 64 + im * 32 + 4 * lh;
            const int which = col >> 10;
            const int hcol  = (col & 1023) >> 6;
            const int dd    = col & 63;
            const int bh    = (rbase >> 11) * 16 + hcol;     // tile within one batch
            unsigned short* const dh = which == 0 ? Qhi : (which == 1 ? Khi : Vhi);
            unsigned short* const dl = which == 0 ? Qlo : (which == 1 ? Klo : Vlo);
            const float sc = which == 0 ? 0.25f : 1.0f;      // fold ATT_SCALE into Q
            const size_t base = (size_t)bh * 131072 + dd;
#pragma unroll
            for (int reg = 0; reg < 16; ++reg) {
                const int row = rbase + (reg & 3) + 8 * (reg >> 2);
                const int n   = row & 2047;
                const float val = (acc[im][jn][reg] + bv) * sc;
                const unsigned short hv = bf16r(val);
                dh[base + (size_t)n * 64] = hv;
                dl[base + (size_t)n * 64] = bf16r(val - bf16f(hv));
            }
        }
}

// ---------------------------------------------------------------------------
__global__ __launch_bounds__(256) void gemm_out(
    const unsigned short* __restrict__ Ahi, const unsigned short* __restrict__ Alo,
    const unsigned short* __restrict__ Bhi, const unsigned short* __restrict__ Blo,
    const float* __restrict__ bias, float* __restrict__ out) {
    GEMM_CORE(Ahi, Alo, Bhi, Blo)
#pragma unroll
    for (int im = 0; im < 2; ++im)
#pragma unroll
        for (int jn = 0; jn < 2; ++jn) {
            const int col   = j0 + wn * 64 + jn * 32 + l31;
            const float bv  = bias[col];
            const int rbase = m0 + wm * 64 + im * 32 + 4 * lh;
#pragma unroll
            for (int reg = 0; reg < 16; ++reg) {
                const int row = rbase + (reg & 3) + 8 * (reg >> 2);
                out[(size_t)row * 1024 + col] = acc[im][jn][reg] + bv;
            }
        }
}

// ---------------------------------------------------------------------------
// MFMA flash attention, swapped-QK^T + in-register P-frags.
// Block: 128 q-rows x one bh; 4 waves x 32 q-rows; KV tile 64.
// S = mfma(K,Q): D[kv][q], lane owns q=l31 (kv in regs across lh pair).
// Softmax: in-reg tree + shfl_xor(32). P-frag: pack hi/lo bf16, exchange
// halves with lane^32. PV = mfma(P,V): D[q-rows][dd=l31] (coalesced epilogue;
// per-row corr via broadcast shfl). LDS 32KB (K,V hi/lo only).
// ---------------------------------------------------------------------------
__global__ __launch_bounds__(256, 3) void attn_mfma(
    const unsigned short* __restrict__ Qhi, const unsigned short* __restrict__ Qlo,
    const unsigned short* __restrict__ Khi, const unsigned short* __restrict__ Klo,
    const unsigned short* __restrict__ Vhi, const unsigned short* __restrict__ Vlo,
    unsigned short* __restrict__ Ohi, unsigned short* __restrict__ Olo) {
    __shared__ unsigned short Kh_s[4096], Kl_s[4096], Vh_s[4096], Vl_s[4096];  // 32 KB

    const int bh = blockIdx.y;
    const int q0 = blockIdx.x * 128;
    const int t  = threadIdx.x;
    const int w  = t >> 6, l = t & 63, l31 = l & 31, lh = l >> 5;
    const size_t bhbase = (size_t)bh * 131072;

    // Q fragments (B-operand): lane holds Q[q0+w*32+l31][kpf*8..+7], kpf=2ks+lh
    bf8 qh[4], ql[4];
    {
        const size_t qb = bhbase + (size_t)(q0 + w * 32 + l31) * 64 + lh * 8;
#pragma unroll
        for (int ks = 0; ks < 4; ++ks) {
            qh[ks] = *(const bf8*)(Qhi + qb + ks * 16);
            ql[ks] = *(const bf8*)(Qlo + qb + ks * 16);
        }
    }

    float m_run = -INFINITY, l_run = 0.f;
    f32x16 O0, O1;
#pragma unroll
    for (int r = 0; r < 16; ++r) { O0[r] = 0.f; O1[r] = 0.f; }

    for (int kt = 0; kt < 32; ++kt) {
        const int k0 = kt * 64;
        __syncthreads();
#pragma unroll
        for (int pass = 0; pass < 2; ++pass) {
            const int c = pass * 256 + t;
            {   // K: r=kv-row, kp=d-piece; fully linear global (4KB/pass)
                const int r = c >> 3, kpc = c & 7;
                const int sl = (((r >> 5) * 8 + kpc) * 32 + (((r & 31) + 2 * kpc) & 31)) * 8;
                const size_t g = bhbase + (size_t)(k0 + r) * 64 + kpc * 8;
                *(bf8*)(Kh_s + sl) = *(const bf8*)(Khi + g);
                *(bf8*)(Kl_s + sl) = *(const bf8*)(Klo + g);
            }
            {   // V gather-transpose: kp=kv-piece, r=dd-row; 128B rows coalesced
                const int kpc = c >> 6, r = c & 63;
                const int sl = (((r >> 5) * 8 + kpc) * 32 + (((r & 31) + 2 * kpc) & 31)) * 8;
                const size_t g = bhbase + (size_t)(k0 + kpc * 8) * 64 + r;
                bf8 vh, vl;
#pragma unroll
                for (int e = 0; e < 8; ++e) {
                    vh[e] = (short)Vhi[g + e * 64];
                    vl[e] = (short)Vlo[g + e * 64];
                }
                *(bf8*)(Vh_s + sl) = vh;
                *(bf8*)(Vl_s + sl) = vl;
            }
        }
        __syncthreads();

        // ---- S = K·Q^T (3-term): D[kv][q], lane col q=l31
        f32x16 s0, s1;
#pragma unroll
        for (int r = 0; r < 16; ++r) { s0[r] = 0.f; s1[r] = 0.f; }
#pragma unroll
        for (int ks = 0; ks < 4; ++ks) {
            const int kpf = ks * 2 + lh;
            const int rot = (l31 + 2 * kpf) & 31;
            const int b0  = (kpf * 32 + rot) * 8;
            const int b1  = ((8 + kpf) * 32 + rot) * 8;
            const bf8 kh0 = *(const bf8*)(Kh_s + b0), kl0 = *(const bf8*)(Kl_s + b0);
            const bf8 kh1 = *(const bf8*)(Kh_s + b1), kl1 = *(const bf8*)(Kl_s + b1);
            s0 = __builtin_amdgcn_mfma_f32_32x32x16_bf16(kh0, qh[ks], s0, 0, 0, 0);
            s0 = __builtin_amdgcn_mfma_f32_32x32x16_bf16(kh0, ql[ks], s0, 0, 0, 0);
            s0 = __builtin_amdgcn_mfma_f32_32x32x16_bf16(kl0, qh[ks], s0, 0, 0, 0);
            s1 = __builtin_amdgcn_mfma_f32_32x32x16_bf16(kh1, qh[ks], s1, 0, 0, 0);
            s1 = __builtin_amdgcn_mfma_f32_32x32x16_bf16(kh1, ql[ks], s1, 0, 0, 0);
            s1 = __builtin_amdgcn_mfma_f32_32x32x16_bf16(kl1, qh[ks], s1, 0, 0, 0);
        }

        // ---- lane-local online softmax (row q=l31 spread over lane pair l,l^32)
        float mx = fmaxf(s0[0], s1[0]);
#pragma unroll
        for (int r = 1; r < 16; ++r) mx = fmaxf(mx, fmaxf(s0[r], s1[r]));
        mx = fmaxf(mx, __shfl_xor(mx, 32));
        const float mn   = fmaxf(m_run, mx);
        const float corr = __expf(m_run - mn);     // 0 on first tile
        m_run = mn;
        float sum = 0.f;
#pragma unroll
        for (int r = 0; r < 16; ++r) {
            s0[r] = __expf(s0[r] - mn); sum += s0[r];
            s1[r] = __expf(s1[r] - mn); sum += s1[r];
        }
        sum += __shfl_xor(sum, 32);
        l_run = l_run * corr + sum;

        // rescale O: row q(r) needs corr from lane q(r) (broadcast shfl)
#pragma unroll
        for (int r = 0; r < 16; ++r) {
            const float cr = __shfl(corr, (r & 3) + 8 * (r >> 2) + 4 * lh);
            O0[r] *= cr; O1[r] *= cr;
        }

        // ---- P-frags in-register + PV (3-term)
#pragma unroll
        for (int ks = 0; ks < 4; ++ks) {
            const int rg = (ks & 1) * 8;
            // tile t = ks>>1 selects s0/s1 (compile-time)
            unsigned int hA0, hA1, hB0, hB1, lA0, lA1, lB0, lB1;
            if (ks < 2) {
                split2(s0[rg + 0], s0[rg + 1], hA0, lA0);
                split2(s0[rg + 2], s0[rg + 3], hA1, lA1);
                split2(s0[rg + 4], s0[rg + 5], hB0, lB0);
                split2(s0[rg + 6], s0[rg + 7], hB1, lB1);
            } else {
                split2(s1[rg + 0], s1[rg + 1], hA0, lA0);
                split2(s1[rg + 2], s1[rg + 3], hA1, lA1);
                split2(s1[rg + 4], s1[rg + 5], hB0, lB0);
                split2(s1[rg + 6], s1[rg + 7], hB1, lB1);
            }
            // exchange: lh=0 sends B-group, lh=1 sends A-group (partner needs it)
            const unsigned int sh0 = lh ? hA0 : hB0, sh1 = lh ? hA1 : hB1;
            const unsigned int sl0 = lh ? lA0 : lB0, sl1 = lh ? lA1 : lB1;
            const unsigned int rh0 = (unsigned int)__shfl_xor((int)sh0, 32);
            const unsigned int rh1 = (unsigned int)__shfl_xor((int)sh1, 32);
            const unsigned int rl0 = (unsigned int)__shfl_xor((int)sl0, 32);
            const unsigned int rl1 = (unsigned int)__shfl_xor((int)sl1, 32);
            union U { unsigned int u[4]; bf8 v; } ph, pl;
            ph.u[0] = lh ? rh0 : hA0;  ph.u[1] = lh ? rh1 : hA1;
            ph.u[2] = lh ? hB0 : rh0;  ph.u[3] = lh ? hB1 : rh1;
            pl.u[0] = lh ? rl0 : lA0;  pl.u[1] = lh ? rl1 : lA1;
            pl.u[2] = lh ? lB0 : rl0;  pl.u[3] = lh ? lB1 : rl1;

            const int kpf = ks * 2 + lh;
            const int rot = (l31 + 2 * kpf) & 31;
            const int v0  = (kpf * 32 + rot) * 8;
            const int v1  = ((8 + kpf) * 32 + rot) * 8;
            const bf8 vh0 = *(const bf8*)(Vh_s + v0), vl0 = *(const bf8*)(Vl_s + v0);
            const bf8 vh1 = *(const bf8*)(Vh_s + v1), vl1 = *(const bf8*)(Vl_s + v1);
            O0 = __builtin_amdgcn_mfma_f32_32x32x16_bf16(ph.v, vh0, O0, 0, 0, 0);
            O0 = __builtin_amdgcn_mfma_f32_32x32x16_bf16(ph.v, vl0, O0, 0, 0, 0);
            O0 = __builtin_amdgcn_mfma_f32_32x32x16_bf16(pl.v, vh0, O0, 0, 0, 0);
            O1 = __builtin_amdgcn_mfma_f32_32x32x16_bf16(ph.v, vh1, O1, 0, 0, 0);
            O1 = __builtin_amdgcn_mfma_f32_32x32x16_bf16(ph.v, vl1, O1, 0, 0, 0);
            O1 = __builtin_amdgcn_mfma_f32_32x32x16_bf16(pl.v, vh1, O1, 0, 0, 0);
        }
    }

    // ---- epilogue: rows q(r), cols dd=l31 (coalesced); 1/l via broadcast shfl
    const int b = bh >> 4, h = bh & 15;
    const float linv_own = 1.f / l_run;
#pragma unroll
    for (int r = 0; r < 16; ++r) {
        const int q = (r & 3) + 8 * (r >> 2) + 4 * lh;
        const float inv = __shfl(linv_own, q);
        const int n = q0 + w * 32 + q;
        const size_t base = ((size_t)b * 2048 + n) * 1024 + h * 64;
        const float v0 = O0[r] * inv, v1 = O1[r] * inv;
        const unsigned short h0 = bf16r(v0), h1 = bf16r(v1);
        Ohi[base + l31]      = h0;  Olo[base + l31]      = bf16r(v0 - bf16f(h0));
        Ohi[base + 32 + l31] = h1;  Olo[base + 32 + l31] = bf16r(v1 - bf16f(h1));
    }
}

// ---------------------------------------------------------------------------
extern "C" void kernel_launch(void* const* d_in, const int* in_sizes, int n_in,
                              void* d_out, int out_size, void* d_ws, size_t ws_size,
                              hipStream_t stream) {
    const float* x     = (const float*)d_in[0];
    const float* w_qkv = (const float*)d_in[1];
    const float* b_qkv = (const float*)d_in[2];
    const float* w_out = (const float*)d_in[3];
    const float* b_out = (const float*)d_in[4];
    float* out = (float*)d_out;

    char* ws = (char*)d_ws;
    unsigned short* Qhi = (unsigned short*)ws; ws += (size_t)8388608 * 2;   // 16 MiB
    unsigned short* Qlo = (unsigned short*)ws; ws += (size_t)8388608 * 2;
    unsigned short* Khi = (unsigned short*)ws; ws += (size_t)8388608 * 2;
    unsigned short* Klo = (unsigned short*)ws; ws += (size_t)8388608 * 2;
    unsigned short* Vhi = (unsigned short*)ws; ws += (size_t)8388608 * 2;
    unsigned short* Vlo = (unsigned short*)ws; ws += (size_t)8388608 * 2;
    unsigned short* Wqh = (unsigned short*)ws; ws += (size_t)3145728 * 2;   // 6 MiB
    unsigned short* Wql = (unsigned short*)ws; ws += (size_t)3145728 * 2;
    unsigned short* Woh = (unsigned short*)ws; ws += (size_t)1048576 * 2;   // 2 MiB
    unsigned short* Wol = (unsigned short*)ws; ws += (size_t)1048576 * 2;
    unsigned short* Xhi = (unsigned short*)ws; ws += (size_t)8388608 * 2;   // 16 MiB
    unsigned short* Xlo = (unsigned short*)ws;
    // X consumed by gemm_qkv before attention writes -> alias attn output:
    unsigned short* AThi = Xhi;
    unsigned short* ATlo = Xlo;

    convert_split<<<8192, 256, 0, stream>>>(x,     Xhi, Xlo, 2097152);
    convert_split<<<3072, 256, 0, stream>>>(w_qkv, Wqh, Wql, 786432);
    convert_split<<<1024, 256, 0, stream>>>(w_out, Woh, Wol, 262144);
    gemm_qkv<<<dim3(24, 64), 256, 0, stream>>>(Xhi, Xlo, Wqh, Wql, b_qkv,
                                               Qhi, Qlo, Khi, Klo, Vhi, Vlo);
    attn_mfma<<<dim3(16, 64), 256, 0, stream>>>(Qhi, Qlo, Khi, Klo, Vhi, Vlo, AThi, ATlo);
    gemm_out<<<dim3(8, 64), 256, 0, stream>>>(AThi, ATlo, Woh, Wol, b_out, out);
}

// Round 13
// 577.569 us; speedup vs baseline: 3.2355x; 1.0845x over previous
//
#include <hip/hip_runtime.h>
#include <math.h>

// fused attention block, MI355X. Round 12 (= round-6 code, 6th resubmit after infra failures):
//   - V transposed at the producer again (r4-verified addr map, quad-packed stores):
//     attn V staging = 4 b128/thread/kt (was 32 scalar loads -> VMEM-issue bound)
//   - truncation-based hi/lo splits in hot paths (precision preserved: lo kept)
//   - T13 exact-skip online-softmax rescale (skips when running max didn't grow)
// ws (128 MiB): Q,K hi/lo + Vt hi/lo 16MiB ea | Wqkv 12 | Wout 4 | X 32 (aliased)

typedef float v4f    __attribute__((ext_vector_type(4)));
typedef float f32x16 __attribute__((ext_vector_type(16)));
typedef short s4     __attribute__((ext_vector_type(4)));
typedef short bf8    __attribute__((ext_vector_type(8)));   // 8 bf16 = 16B MFMA frag

__device__ __forceinline__ unsigned short bf16r(float f) {   // RNE f32->bf16
    unsigned int u = __float_as_uint(f);
    u += 0x7FFFu + ((u >> 16) & 1u);
    return (unsigned short)(u >> 16);
}
__device__ __forceinline__ float bf16f(unsigned short h) {
    return __uint_as_float(((unsigned int)h) << 16);
}
// truncation split: hi = truncate(v), lo = truncate(v - hi). hi+lo ~ 2^-16 rel.
__device__ __forceinline__ void splitt(float v, unsigned short& h, unsigned short& lo2) {
    const unsigned int u  = __float_as_uint(v);
    const unsigned int hm = u & 0xFFFF0000u;
    h   = (unsigned short)(u >> 16);
    lo2 = (unsigned short)(__float_as_uint(v - __uint_as_float(hm)) >> 16);
}
// pack two values' truncation split into packed-bf16 dwords
__device__ __forceinline__ void split2t(float a, float b, unsigned int& hi, unsigned int& lo) {
    const unsigned int ua = __float_as_uint(a), ub = __float_as_uint(b);
    const unsigned int ha = ua & 0xFFFF0000u,  hb = ub & 0xFFFF0000u;
    hi = (ha >> 16) | hb;
    const float la = a - __uint_as_float(ha), lb = b - __uint_as_float(hb);
    lo = (__float_as_uint(la) >> 16) | (__float_as_uint(lb) & 0xFFFF0000u);
}

// ---------------------------------------------------------------------------
__global__ __launch_bounds__(256) void convert_split(const float* __restrict__ in,
                                                     unsigned short* __restrict__ hi,
                                                     unsigned short* __restrict__ lo,
                                                     int n4) {
    const int i = blockIdx.x * 256 + threadIdx.x;
    if (i >= n4) return;
    v4f xv = ((const v4f*)in)[i];
    s4 h, l;
#pragma unroll
    for (int j = 0; j < 4; ++j) {
        unsigned short hv = bf16r(xv[j]);
        h[j] = (short)hv;
        l[j] = (short)bf16r(xv[j] - bf16f(hv));
    }
    ((s4*)hi)[i] = h;
    ((s4*)lo)[i] = l;
}

// ---------------------------------------------------------------------------
// GEMM core (verified r4): 128x128 tile, BK=32, 4 waves 2x2, 3-term split.
// ---------------------------------------------------------------------------
#define GEMM_CORE(AHI, ALO, BHI, BLO)                                                      \
    __shared__ unsigned short lAh[4096], lAl[4096], lBh[4096], lBl[4096];                  \
    const int m0 = blockIdx.y * 128;                                                       \
    const int j0 = blockIdx.x * 128;                                                       \
    const int t  = threadIdx.x;                                                            \
    const int kp  = t & 3;                                                                 \
    const int r0  = t >> 2;                                                                \
    const int sks = kp >> 1, skh = kp & 1;                                                 \
    const int l   = t & 63;                                                                \
    const int wid = t >> 6;                                                                \
    const int wm  = wid >> 1, wn = wid & 1;                                                \
    const int l31 = l & 31, lh = l >> 5;                                                   \
    int offA[2][2], offB[2][2];                                                            \
    _Pragma("unroll") for (int im = 0; im < 2; ++im)                                       \
    _Pragma("unroll") for (int ks = 0; ks < 2; ++ks) {                                     \
        const int kpr = ks * 2 + lh;                                                       \
        const int rot = (l31 + 2 * kpr) & 31;                                              \
        offA[im][ks] = ((((wm*2+im)*2+ks)*64) + lh*32 + rot) * 8;                          \
        offB[im][ks] = ((((wn*2+im)*2+ks)*64) + lh*32 + rot) * 8;                          \
    }                                                                                      \
    f32x16 acc[2][2];                                                                      \
    _Pragma("unroll") for (int i = 0; i < 2; ++i)                                          \
    _Pragma("unroll") for (int j = 0; j < 2; ++j)                                          \
    _Pragma("unroll") for (int r = 0; r < 16; ++r) acc[i][j][r] = 0.f;                     \
    for (int kt = 0; kt < 32; ++kt) {                                                      \
        __syncthreads();                                                                   \
        const int kb = kt * 32 + kp * 8;                                                   \
        _Pragma("unroll") for (int hh = 0; hh < 2; ++hh) {                                 \
            const int r  = r0 + hh * 64;                                                   \
            const int sl = (((r >> 5) * 2 + sks) * 64 + skh * 32 + (((r & 31) + 2 * kp) & 31)) * 8; \
            const size_t ga = (size_t)(m0 + r) * 1024 + kb;                                \
            const size_t gb = (size_t)(j0 + r) * 1024 + kb;                                \
            *(bf8*)(lAh + sl) = *(const bf8*)(AHI + ga);                                   \
            *(bf8*)(lAl + sl) = *(const bf8*)(ALO + ga);                                   \
            *(bf8*)(lBh + sl) = *(const bf8*)(BHI + gb);                                   \
            *(bf8*)(lBl + sl) = *(const bf8*)(BLO + gb);                                   \
        }                                                                                  \
        __syncthreads();                                                                   \
        _Pragma("unroll") for (int ks = 0; ks < 2; ++ks) {                                 \
            bf8 ah[2], al2[2], bh[2], bl2[2];                                              \
            _Pragma("unroll") for (int im = 0; im < 2; ++im) {                             \
                ah[im]  = *(const bf8*)(lAh + offA[im][ks]);                               \
                al2[im] = *(const bf8*)(lAl + offA[im][ks]);                               \
                bh[im]  = *(const bf8*)(lBh + offB[im][ks]);                               \
                bl2[im] = *(const bf8*)(lBl + offB[im][ks]);                               \
            }                                                                              \
            _Pragma("unroll") for (int im = 0; im < 2; ++im)                               \
            _Pragma("unroll") for (int jn = 0; jn < 2; ++jn) {                             \
                acc[im][jn] = __builtin_amdgcn_mfma_f32_32x32x16_bf16(ah[im],  bh[jn],  acc[im][jn], 0, 0, 0); \
                acc[im][jn] = __builtin_amdgcn_mfma_f32_32x32x16_bf16(ah[im],  bl2[jn], acc[im][jn], 0, 0, 0); \
                acc[im][jn] = __builtin_amdgcn_mfma_f32_32x32x16_bf16(al2[im], bh[jn],  acc[im][jn], 0, 0, 0); \
            }                                                                              \
        }                                                                                  \
    }

// ---------------------------------------------------------------------------
// QKV GEMM: Q (x0.25), K natural [bh][n][64]; V TRANSPOSED [bh][dd][n] (r4 map,
// quad-packed 8B stores). All split hi/lo (truncation).
// ---------------------------------------------------------------------------
__global__ __launch_bounds__(256) void gemm_qkv(
    const unsigned short* __restrict__ Ahi, const unsigned short* __restrict__ Alo,
    const unsigned short* __restrict__ Bhi, const unsigned short* __restrict__ Blo,
    const float* __restrict__ bias,
    unsigned short* __restrict__ Qhi, unsigned short* __restrict__ Qlo,
    unsigned short* __restrict__ Khi, unsigned short* __restrict__ Klo,
    unsigned short* __restrict__ Vhi, unsigned short* __restrict__ Vlo) {
    GEMM_CORE(Ahi, Alo, Bhi, Blo)
#pragma unroll
    for (int im = 0; im < 2; ++im)
#pragma unroll
        for (int jn = 0; jn < 2; ++jn) {
            const int col   = j0 + wn * 64 + jn * 32 + l31;
            const float bv  = bias[col];
            const int rbase = m0 + wm * 64 + im * 32 + 4 * lh;
            const int which = col >> 10;                     // uniform per block
            const int hcol  = (col & 1023) >> 6;
            const int dd    = col & 63;
            const int bh    = (rbase >> 11) * 16 + hcol;     // tile within one batch
            if (which == 2) {
                // Vt [bh][dd][n]: quad-packed along n (regs within a quad are n,n+1,n+2,n+3)
                const size_t vbase = (size_t)bh * 131072 + (size_t)dd * 2048 + (rbase & 2047);
#pragma unroll
                for (int rq = 0; rq < 4; ++rq) {
                    s4 hq, lq;
#pragma unroll
                    for (int e = 0; e < 4; ++e) {
                        const float val = acc[im][jn][rq * 4 + e] + bv;
                        unsigned short hv, lv;
                        splitt(val, hv, lv);
                        hq[e] = (short)hv; lq[e] = (short)lv;
                    }
                    *(s4*)(Vhi + vbase + 8 * rq) = hq;
                    *(s4*)(Vlo + vbase + 8 * rq) = lq;
                }
            } else {
                unsigned short* const dh = which == 0 ? Qhi : Khi;
                unsigned short* const dl = which == 0 ? Qlo : Klo;
                const float sc = which == 0 ? 0.25f : 1.0f;  // fold ATT_SCALE into Q
                const size_t base = (size_t)bh * 131072 + dd;
#pragma unroll
                for (int reg = 0; reg < 16; ++reg) {
                    const int row = rbase + (reg & 3) + 8 * (reg >> 2);
                    const int n   = row & 2047;
                    const float val = (acc[im][jn][reg] + bv) * sc;
                    unsigned short hv, lv;
                    splitt(val, hv, lv);
                    dh[base + (size_t)n * 64] = hv;
                    dl[base + (size_t)n * 64] = lv;
                }
            }
        }
}

// ---------------------------------------------------------------------------
__global__ __launch_bounds__(256) void gemm_out(
    const unsigned short* __restrict__ Ahi, const unsigned short* __restrict__ Alo,
    const unsigned short* __restrict__ Bhi, const unsigned short* __restrict__ Blo,
    const float* __restrict__ bias, float* __restrict__ out) {
    GEMM_CORE(Ahi, Alo, Bhi, Blo)
#pragma unroll
    for (int im = 0; im < 2; ++im)
#pragma unroll
        for (int jn = 0; jn < 2; ++jn) {
            const int col   = j0 + wn * 64 + jn * 32 + l31;
            const float bv  = bias[col];
            const int rbase = m0 + wm * 64 + im * 32 + 4 * lh;
#pragma unroll
            for (int reg = 0; reg < 16; ++reg) {
                const int row = rbase + (reg & 3) + 8 * (reg >> 2);
                out[(size_t)row * 1024 + col] = acc[im][jn][reg] + bv;
            }
        }
}

// ---------------------------------------------------------------------------
// MFMA flash attention, swapped-QK^T + in-register P-frags.
// Block: 128 q-rows x one bh; 4 waves x 32 q-rows; KV tile 64.
// K natural [bh][n][64], Vt [bh][dd][n]: BOTH staged with 4 b128/thread/kt.
// Softmax lane-local (row q=l31 over lane pair l,l^32); T13 exact-skip rescale.
// ---------------------------------------------------------------------------
__global__ __launch_bounds__(256, 3) void attn_mfma(
    const unsigned short* __restrict__ Qhi, const unsigned short* __restrict__ Qlo,
    const unsigned short* __restrict__ Khi, const unsigned short* __restrict__ Klo,
    const unsigned short* __restrict__ Vhi, const unsigned short* __restrict__ Vlo,
    unsigned short* __restrict__ Ohi, unsigned short* __restrict__ Olo) {
    __shared__ unsigned short Kh_s[4096], Kl_s[4096], Vh_s[4096], Vl_s[4096];  // 32 KB

    const int bh = blockIdx.y;
    const int q0 = blockIdx.x * 128;
    const int t  = threadIdx.x;
    const int w  = t >> 6, l = t & 63, l31 = l & 31, lh = l >> 5;
    const size_t bhbase = (size_t)bh * 131072;

    // Q fragments (B-operand): lane holds Q[q0+w*32+l31][kpf*8..+7], kpf=2ks+lh
    bf8 qh[4], ql[4];
    {
        const size_t qb = bhbase + (size_t)(q0 + w * 32 + l31) * 64 + lh * 8;
#pragma unroll
        for (int ks = 0; ks < 4; ++ks) {
            qh[ks] = *(const bf8*)(Qhi + qb + ks * 16);
            ql[ks] = *(const bf8*)(Qlo + qb + ks * 16);
        }
    }

    float m_run = -INFINITY, l_run = 0.f;
    f32x16 O0, O1;
#pragma unroll
    for (int r = 0; r < 16; ++r) { O0[r] = 0.f; O1[r] = 0.f; }

    for (int kt = 0; kt < 32; ++kt) {
        const int k0 = kt * 64;
        __syncthreads();
#pragma unroll
        for (int pass = 0; pass < 2; ++pass) {
            const int c = pass * 256 + t;
            const int r = c >> 3, kpc = c & 7;
            const int sl = (((r >> 5) * 8 + kpc) * 32 + (((r & 31) + 2 * kpc) & 31)) * 8;
            {   // K: r = kv-row, kpc = d-piece
                const size_t g = bhbase + (size_t)(k0 + r) * 64 + kpc * 8;
                *(bf8*)(Kh_s + sl) = *(const bf8*)(Khi + g);
                *(bf8*)(Kl_s + sl) = *(const bf8*)(Klo + g);
            }
            {   // Vt: r = dd-row, kpc = kv-piece
                const size_t g = bhbase + (size_t)r * 2048 + k0 + kpc * 8;
                *(bf8*)(Vh_s + sl) = *(const bf8*)(Vhi + g);
                *(bf8*)(Vl_s + sl) = *(const bf8*)(Vlo + g);
            }
        }
        __syncthreads();

        // ---- S = K·Q^T (3-term): D[kv][q], lane col q=l31
        f32x16 s0, s1;
#pragma unroll
        for (int r = 0; r < 16; ++r) { s0[r] = 0.f; s1[r] = 0.f; }
#pragma unroll
        for (int ks = 0; ks < 4; ++ks) {
            const int kpf = ks * 2 + lh;
            const int rot = (l31 + 2 * kpf) & 31;
            const int b0  = (kpf * 32 + rot) * 8;
            const int b1  = ((8 + kpf) * 32 + rot) * 8;
            const bf8 kh0 = *(const bf8*)(Kh_s + b0), kl0 = *(const bf8*)(Kl_s + b0);
            const bf8 kh1 = *(const bf8*)(Kh_s + b1), kl1 = *(const bf8*)(Kl_s + b1);
            s0 = __builtin_amdgcn_mfma_f32_32x32x16_bf16(kh0, qh[ks], s0, 0, 0, 0);
            s0 = __builtin_amdgcn_mfma_f32_32x32x16_bf16(kh0, ql[ks], s0, 0, 0, 0);
            s0 = __builtin_amdgcn_mfma_f32_32x32x16_bf16(kl0, qh[ks], s0, 0, 0, 0);
            s1 = __builtin_amdgcn_mfma_f32_32x32x16_bf16(kh1, qh[ks], s1, 0, 0, 0);
            s1 = __builtin_amdgcn_mfma_f32_32x32x16_bf16(kh1, ql[ks], s1, 0, 0, 0);
            s1 = __builtin_amdgcn_mfma_f32_32x32x16_bf16(kl1, qh[ks], s1, 0, 0, 0);
        }

        // ---- lane-local online softmax with T13 exact-skip rescale
        float mx = fmaxf(s0[0], s1[0]);
#pragma unroll
        for (int r = 1; r < 16; ++r) mx = fmaxf(mx, fmaxf(s0[r], s1[r]));
        mx = fmaxf(mx, __shfl_xor(mx, 32));
        if (__any(mx > m_run)) {
            const float mn   = fmaxf(m_run, mx);
            const float corr = __expf(m_run - mn);   // ==1 for lanes that didn't grow
            m_run = mn;
            l_run *= corr;
#pragma unroll
            for (int r = 0; r < 16; ++r) {
                const float cr = __shfl(corr, (r & 3) + 8 * (r >> 2) + 4 * lh);
                O0[r] *= cr; O1[r] *= cr;
            }
        }
        float sum = 0.f;
#pragma unroll
        for (int r = 0; r < 16; ++r) {
            s0[r] = __expf(s0[r] - m_run); sum += s0[r];
            s1[r] = __expf(s1[r] - m_run); sum += s1[r];
        }
        sum += __shfl_xor(sum, 32);
        l_run += sum;

        // ---- P-frags in-register (truncation split) + PV (3-term)
#pragma unroll
        for (int ks = 0; ks < 4; ++ks) {
            const int rg = (ks & 1) * 8;
            unsigned int hA0, hA1, hB0, hB1, lA0, lA1, lB0, lB1;
            if (ks < 2) {
                split2t(s0[rg + 0], s0[rg + 1], hA0, lA0);
                split2t(s0[rg + 2], s0[rg + 3], hA1, lA1);
                split2t(s0[rg + 4], s0[rg + 5], hB0, lB0);
                split2t(s0[rg + 6], s0[rg + 7], hB1, lB1);
            } else {
                split2t(s1[rg + 0], s1[rg + 1], hA0, lA0);
                split2t(s1[rg + 2], s1[rg + 3], hA1, lA1);
                split2t(s1[rg + 4], s1[rg + 5], hB0, lB0);
                split2t(s1[rg + 6], s1[rg + 7], hB1, lB1);
            }
            // exchange with partner lane l^32 (lh=0 sends B-group, lh=1 sends A-group)
            const unsigned int sh0 = lh ? hA0 : hB0, sh1 = lh ? hA1 : hB1;
            const unsigned int sl0 = lh ? lA0 : lB0, sl1 = lh ? lA1 : lB1;
            const unsigned int rh0 = (unsigned int)__shfl_xor((int)sh0, 32);
            const unsigned int rh1 = (unsigned int)__shfl_xor((int)sh1, 32);
            const unsigned int rl0 = (unsigned int)__shfl_xor((int)sl0, 32);
            const unsigned int rl1 = (unsigned int)__shfl_xor((int)sl1, 32);
            union U { unsigned int u[4]; bf8 v; } ph, pl;
            ph.u[0] = lh ? rh0 : hA0;  ph.u[1] = lh ? rh1 : hA1;
            ph.u[2] = lh ? hB0 : rh0;  ph.u[3] = lh ? hB1 : rh1;
            pl.u[0] = lh ? rl0 : lA0;  pl.u[1] = lh ? rl1 : lA1;
            pl.u[2] = lh ? lB0 : rl0;  pl.u[3] = lh ? lB1 : rl1;

            const int kpf = ks * 2 + lh;
            const int rot = (l31 + 2 * kpf) & 31;
            const int v0  = (kpf * 32 + rot) * 8;
            const int v1  = ((8 + kpf) * 32 + rot) * 8;
            const bf8 vh0 = *(const bf8*)(Vh_s + v0), vl0 = *(const bf8*)(Vl_s + v0);
            const bf8 vh1 = *(const bf8*)(Vh_s + v1), vl1 = *(const bf8*)(Vl_s + v1);
            O0 = __builtin_amdgcn_mfma_f32_32x32x16_bf16(ph.v, vh0, O0, 0, 0, 0);
            O0 = __builtin_amdgcn_mfma_f32_32x32x16_bf16(ph.v, vl0, O0, 0, 0, 0);
            O0 = __builtin_amdgcn_mfma_f32_32x32x16_bf16(pl.v, vh0, O0, 0, 0, 0);
            O1 = __builtin_amdgcn_mfma_f32_32x32x16_bf16(ph.v, vh1, O1, 0, 0, 0);
            O1 = __builtin_amdgcn_mfma_f32_32x32x16_bf16(ph.v, vl1, O1, 0, 0, 0);
            O1 = __builtin_amdgcn_mfma_f32_32x32x16_bf16(pl.v, vh1, O1, 0, 0, 0);
        }
    }

    // ---- epilogue: rows q(r), cols dd=l31 (coalesced); 1/l via broadcast shfl
    const int b = bh >> 4, h = bh & 15;
    const float linv_own = 1.f / l_run;
#pragma unroll
    for (int r = 0; r < 16; ++r) {
        const int q = (r & 3) + 8 * (r >> 2) + 4 * lh;
        const float inv = __shfl(linv_own, q);
        const int n = q0 + w * 32 + q;
        const size_t base = ((size_t)b * 2048 + n) * 1024 + h * 64;
        const float v0 = O0[r] * inv, v1 = O1[r] * inv;
        unsigned short h0, l0s, h1, l1s;
        splitt(v0, h0, l0s);
        splitt(v1, h1, l1s);
        Ohi[base + l31]      = h0;  Olo[base + l31]      = l0s;
        Ohi[base + 32 + l31] = h1;  Olo[base + 32 + l31] = l1s;
    }
}

// ---------------------------------------------------------------------------
extern "C" void kernel_launch(void* const* d_in, const int* in_sizes, int n_in,
                              void* d_out, int out_size, void* d_ws, size_t ws_size,
                              hipStream_t stream) {
    const float* x     = (const float*)d_in[0];
    const float* w_qkv = (const float*)d_in[1];
    const float* b_qkv = (const float*)d_in[2];
    const float* w_out = (const float*)d_in[3];
    const float* b_out = (const float*)d_in[4];
    float* out = (float*)d_out;

    char* ws = (char*)d_ws;
    unsigned short* Qhi = (unsigned short*)ws; ws += (size_t)8388608 * 2;   // 16 MiB
    unsigned short* Qlo = (unsigned short*)ws; ws += (size_t)8388608 * 2;
    unsigned short* Khi = (unsigned short*)ws; ws += (size_t)8388608 * 2;
    unsigned short* Klo = (unsigned short*)ws; ws += (size_t)8388608 * 2;
    unsigned short* Vhi = (unsigned short*)ws; ws += (size_t)8388608 * 2;   // Vt [bh][dd][n]
    unsigned short* Vlo = (unsigned short*)ws; ws += (size_t)8388608 * 2;
    unsigned short* Wqh = (unsigned short*)ws; ws += (size_t)3145728 * 2;   // 6 MiB
    unsigned short* Wql = (unsigned short*)ws; ws += (size_t)3145728 * 2;
    unsigned short* Woh = (unsigned short*)ws; ws += (size_t)1048576 * 2;   // 2 MiB
    unsigned short* Wol = (unsigned short*)ws; ws += (size_t)1048576 * 2;
    unsigned short* Xhi = (unsigned short*)ws; ws += (size_t)8388608 * 2;   // 16 MiB
    unsigned short* Xlo = (unsigned short*)ws;
    // X consumed by gemm_qkv before attention writes -> alias attn output:
    unsigned short* AThi = Xhi;
    unsigned short* ATlo = Xlo;

    convert_split<<<8192, 256, 0, stream>>>(x,     Xhi, Xlo, 2097152);
    convert_split<<<3072, 256, 0, stream>>>(w_qkv, Wqh, Wql, 786432);
    convert_split<<<1024, 256, 0, stream>>>(w_out, Woh, Wol, 262144);
    gemm_qkv<<<dim3(24, 64), 256, 0, stream>>>(Xhi, Xlo, Wqh, Wql, b_qkv,
                                               Qhi, Qlo, Khi, Klo, Vhi, Vlo);
    attn_mfma<<<dim3(16, 64), 256, 0, stream>>>(Qhi, Qlo, Khi, Klo, Vhi, Vlo, AThi, ATlo);
    gemm_out<<<dim3(8, 64), 256, 0, stream>>>(AThi, ATlo, Woh, Wol, b_out, out);
}